// Round 7
// baseline (1660.258 us; speedup 1.0000x reference)
//
#include <hip/hip_runtime.h>
#include <math.h>

// RPN forward: fused conv3x3+relu (all levels, one dispatch) -> fused 1x1
// heads -> per-level topk+decode (fused) -> sort+gather (fused) ->
// group-gated NMS -> per-image top-100.
// Precision: f64 accumulation + f64 logits/regs/h so all selection decisions
// match the float64 numpy reference (~1e-13 rel; min decision gap ~1e-8).
// Input order: setup_inputs() interleaves fmap{i}/priors{i}:
//   d_in[2l]=fmap_l, d_in[2l+1]=priors_l, then conv_w..imsizes at 10..16.
// R3: reg double-buffer ballooned VGPR (252) -> occ 11%. R4: f32 LDS ->
// cvt ate 25% of VALU. R5: 44.5KB LDS -> occ 29%; f64 weights blew L2.
// R6: CI4 + XCD swizzle -> FETCH fixed, but VALU 66%: weight LDS round-trip
// (stage+2 barriers+b128 reads, 73M bank-conflict cycles) was the tax.
// R7: wave=64px, acc=16co/lane; weights via readfirstlane-uniform scalar
// loads (SGPR broadcast, no LDS); LDS = input halo only (7.7KB).

#define N_IMG 2
#define C_CH  256
#define D_PER 2147           // 500*4 + 147
#define K_TOT 4294           // N_IMG * D_PER
#define K_PAD 8192
#define CONV_BLOCKS 1912
#define CPX 239              // CONV_BLOCKS / 8 XCDs (exact)

__constant__ int c_Ml[5]     = {30000, 7500, 1875, 507, 147};
__constant__ int c_kl[5]     = {500, 500, 500, 500, 147};
__constant__ int c_lvoff[5]  = {0, 500, 1000, 1500, 2000};
__constant__ int c_logoff[5] = {0, 60000, 75000, 78750, 79764};   // 6*cumE
__constant__ int c_regoff[5] = {0, 240000, 300000, 315000, 319056}; // 24*cumE
__constant__ int c_fs[5]     = {100, 50, 25, 13, 7};
__constant__ int c_npt[5]    = {13, 7, 4, 2, 1};
__constant__ int c_E[5]      = {10000, 2500, 625, 169, 49};
__constant__ int c_cumbl[6]  = {0, 1352, 1744, 1872, 1904, 1912}; // conv blocks
__constant__ int c_hcum[6]   = {0, 157, 197, 207, 210, 211};      // head chunks
// h element offsets per level (2 imgs * 256 ch * E)
__constant__ size_t c_hoff[5] = {0, 5120000, 6400000, 6720000, 6806528};

// ------- weight repack+convert: slabs of 4608 f64 = [ci8][tap9][co64] ----
// slab (cobi*32+ch) is consumed per conv ci-chunk iteration (CI_CHUNK=8).
__global__ void transpose_w_kernel(const float* __restrict__ w,
                                   double* __restrict__ wT2) {
  int i = blockIdx.x * 256 + threadIdx.x;
  if (i >= 589824) return;
  int q = i % 4608;
  int slab = i / 4608;
  int cobi = slab >> 5, ch = slab & 31;
  int ci = q / 576;
  int rem = q % 576;
  int tap = rem / 64, co = rem & 63;
  wT2[i] =
      (double)w[(size_t)(cobi * 64 + co) * 2304 + (ch * 8 + ci) * 9 + tap];
}

// ------- fused conv3x3 (SAME) + bias + relu, all 5 levels, f64 acc -------
// block: 256 thr = 4 waves; wave = 64 px (8x8 tile), owns co16 group wv.
// acc[16] f64 per lane. Weights: scalar (uniform) loads, no LDS. Input:
// 8-ci halo in LDS (7.7KB), 32 chunks.
template <typename T>
__global__ __launch_bounds__(256) void conv_fused_kernel(
    const float* __restrict__ x0, const float* __restrict__ x1,
    const float* __restrict__ x2, const float* __restrict__ x3,
    const float* __restrict__ x4, const double* __restrict__ wT2,
    const float* __restrict__ bias, T* __restrict__ h) {
  __shared__ double s_in[8 * 120];   // [ci][10 rows x 12 (pad)] doubles
  int tid = threadIdx.x;
  // XCD-aware swizzle: consecutive logical bids (same cobi slab) -> same XCD
  int bid = (blockIdx.x & 7) * CPX + (blockIdx.x >> 3);
  int l = 0;
  while (bid >= c_cumbl[l + 1]) ++l;
  int r = bid - c_cumbl[l];
  int fs = c_fs[l], npt = c_npt[l];
  int tiles = npt * npt;
  int tile = r % tiles;
  int cn = r / tiles;
  int cobi = cn & 3, n = cn >> 2;
  int ptx = tile % npt, pty = tile / npt;
  int px0 = ptx * 8, py0 = pty * 8;
  int E = fs * fs;
  const float* xl;
  switch (l) {
    case 0: xl = x0; break;
    case 1: xl = x1; break;
    case 2: xl = x2; break;
    case 3: xl = x3; break;
    default: xl = x4; break;
  }
  const float* xn = xl + (size_t)n * C_CH * E;
  T* hl = h + c_hoff[l];

  int lane = tid & 63;
  int wvu = __builtin_amdgcn_readfirstlane(tid >> 6);  // co16 group, uniform
  int prow = lane >> 3, pcol = lane & 7;

  // hoisted staging descriptors: 800 halo elems over 256 threads (4 slots)
  int in_dst[4], in_src[4];
#pragma unroll
  for (int it = 0; it < 4; ++it) {
    int idx = tid + it * 256;
    in_dst[it] = -1;
    in_src[it] = -1;
    if (idx < 800) {
      int ci = idx / 100, rr2 = idx % 100;
      int hy = rr2 / 10, hx = rr2 % 10;
      int gy = py0 - 1 + hy, gx = px0 - 1 + hx;
      in_dst[it] = ci * 120 + hy * 12 + hx;
      if (gy >= 0 && gy < fs && gx >= 0 && gx < fs)
        in_src[it] = ci * E + gy * fs + gx;
    }
  }

  double acc[16];
#pragma unroll
  for (int c = 0; c < 16; ++c) acc[c] = 0.0;

  // uniform weight base for this block's cobi and this wave's co16
  const double* __restrict__ wbase =
      wT2 + (size_t)(cobi * 32) * 4608 + wvu * 16;

  for (int ch = 0; ch < 32; ++ch) {
    const float* xc = xn + (size_t)(ch * 8) * E;
#pragma unroll
    for (int it = 0; it < 4; ++it) {
      if (in_dst[it] >= 0)
        s_in[in_dst[it]] = (in_src[it] >= 0) ? (double)xc[in_src[it]] : 0.0;
    }
    __syncthreads();
    const double* __restrict__ wch = wbase + (size_t)ch * 4608;
#pragma unroll
    for (int ci = 0; ci < 8; ++ci) {
      const double* inp = &s_in[ci * 120];
#pragma unroll
      for (int ky = 0; ky < 3; ++ky) {
        const double* ip = inp + (prow + ky) * 12 + pcol;
        double iv[3];
        iv[0] = ip[0];
        iv[1] = ip[1];
        iv[2] = ip[2];
#pragma unroll
        for (int kx = 0; kx < 3; ++kx) {
          const double* __restrict__ wk = wch + (ci * 9 + ky * 3 + kx) * 64;
          double ivx = iv[kx];
#pragma unroll
          for (int c = 0; c < 16; ++c)
            acc[c] = fma(wk[c], ivx, acc[c]);
        }
      }
    }
    __syncthreads();
  }

  int gy = py0 + prow, gx = px0 + pcol;
  if (gy < fs && gx < fs) {
#pragma unroll
    for (int c = 0; c < 16; ++c) {
      int co = cobi * 64 + wvu * 16 + c;
      double v = acc[c] + (double)bias[co];
      hl[((size_t)n * C_CH + co) * E + gy * fs + gx] = (T)fmax(v, 0.0);
    }
  }
}

// ------- fused 1x1 heads: 64 px x 4 c-groups per block, LDS reduce -------
template <typename T>
__global__ __launch_bounds__(256) void heads_fused_kernel(
    const T* __restrict__ h, const float* __restrict__ logw,
    const float* __restrict__ logb, const float* __restrict__ regw,
    const float* __restrict__ regb, double* __restrict__ logits,
    double* __restrict__ regs) {
  __shared__ float s_wh[256][16];      // [c][j], j<15 used
  __shared__ double s_red[4][15][64];
  int tid = threadIdx.x;
  int n = blockIdx.y;
  int cidx = blockIdx.x;
  int l = 0;
  while (cidx >= c_hcum[l + 1]) ++l;
  int chunk = cidx - c_hcum[l];
  int E = c_E[l];
  int px0 = chunk * 64;
  const T* hl = h + c_hoff[l];
  double* logits_l = logits + c_logoff[l];
  double* regs_l = regs + c_regoff[l];

  for (int idx = tid; idx < 4096; idx += 256) {
    int c = idx >> 4, j = idx & 15;
    float v = 0.f;
    if (j < 3) v = logw[j * 256 + c];
    else if (j < 15) v = regw[(j - 3) * 256 + c];
    s_wh[c][j] = v;
  }
  __syncthreads();

  int p = tid & 63, c4 = tid >> 6;
  int pix = px0 + p;
  bool act = pix < E;
  double acc[15];
#pragma unroll
  for (int j = 0; j < 15; j++) acc[j] = 0.0;
  if (act) {
    const T* hp = hl + ((size_t)n * C_CH + c4 * 64) * E + pix;
    for (int cc = 0; cc < 64; ++cc) {
      double hv = (double)hp[(size_t)cc * E];
      const float* wr = &s_wh[c4 * 64 + cc][0];
#pragma unroll
      for (int j = 0; j < 15; j++)
        acc[j] = fma((double)wr[j], hv, acc[j]);
    }
  }
#pragma unroll
  for (int j = 0; j < 15; j++) s_red[c4][j][p] = acc[j];
  __syncthreads();
  if (act) {
    int M = E * 3;
    for (int j = c4; j < 15; j += 4) {
      double v = s_red[0][j][p] + s_red[1][j][p] + s_red[2][j][p] +
                 s_red[3][j][p];
      if (j < 3) {
        logits_l[(size_t)n * M + pix * 3 + j] = v + (double)logb[j];
      } else {
        int rj = j - 3, a = rj >> 2, coord = rj & 3;
        regs_l[((size_t)n * M + pix * 3 + a) * 4 + coord] =
            v + (double)regb[rj];
      }
    }
  }
}

// ------- top-k per (img,level) + inline decode (fused) -------------------
__device__ __forceinline__ unsigned long long d2key(double v) {
  unsigned long long ub = (unsigned long long)__double_as_longlong(v);
  return (ub >> 63) ? ~ub : (ub | 0x8000000000000000ull);
}

#define TK_CH 30
__global__ __launch_bounds__(1024) void topk_decode_kernel(
    const double* __restrict__ logits, const double* __restrict__ regs,
    const float* __restrict__ p0, const float* __restrict__ p1,
    const float* __restrict__ p2, const float* __restrict__ p3,
    const float* __restrict__ p4, const int* __restrict__ imsizes,
    double* __restrict__ cand_score, double* __restrict__ cand_box,
    int* __restrict__ cand_group, int* __restrict__ cand_valid) {
  int bid = blockIdx.x;
  int n = bid / 5, l = bid % 5;
  int M = c_Ml[l], k = c_kl[l];
  const double* lg = logits + c_logoff[l] + (size_t)n * M;
  int tid = threadIdx.x;
  __shared__ int histw[16][256];
  __shared__ int hist[256];
  __shared__ int s_sel[512];
  __shared__ unsigned long long s_prefix;
  __shared__ int s_r;
  if (tid == 0) { s_prefix = 0ull; s_r = k; }

  int chunk = (M + 1023) >> 10;     // <= 30
  int i0 = tid * chunk, i1 = min(M, i0 + chunk);
  int cnt = i1 - i0;
  if (cnt < 0) cnt = 0;
  unsigned long long kv[TK_CH];
#pragma unroll
  for (int q = 0; q < TK_CH; q++)
    if (q < cnt) kv[q] = d2key(lg[i0 + q]);
  int wid = tid >> 6;
  __syncthreads();

  for (int pass = 0; pass < 8; ++pass) {
    int shift = 56 - pass * 8;
    for (int i = tid; i < 4096; i += 1024) ((int*)histw)[i] = 0;
    __syncthreads();
    unsigned long long pfx = s_prefix;
    int rr = s_r;
#pragma unroll
    for (int q = 0; q < TK_CH; q++) {
      if (q < cnt) {
        unsigned long long u = kv[q];
        if (pass == 0 || (u >> (shift + 8)) == pfx)
          atomicAdd(&histw[wid][(int)((u >> shift) & 255ull)], 1);
      }
    }
    __syncthreads();
    if (tid < 256) {
      int s = 0;
#pragma unroll
      for (int w = 0; w < 16; w++) s += histw[w][tid];
      hist[tid] = s;
    }
    __syncthreads();
    if (tid == 0) {
      int s = 0, beta = 0;
      for (int b = 255; b >= 0; --b) {
        if (s + hist[b] >= rr) { beta = b; break; }
        s += hist[b];
      }
      s_prefix = (pfx << 8) | (unsigned long long)beta;
      s_r = rr - s;
    }
    __syncthreads();
  }
  unsigned long long T = s_prefix;
  int need = s_r;
  int cgt = 0, ceq = 0;
#pragma unroll
  for (int q = 0; q < TK_CH; q++) {
    if (q < cnt) {
      cgt += (kv[q] > T);
      ceq += (kv[q] == T);
    }
  }
  __shared__ int sgt[1024], seq[1024];
  sgt[tid] = cgt;
  seq[tid] = ceq;
  __syncthreads();
  for (int o = 1; o < 1024; o <<= 1) {
    int a = (tid >= o) ? sgt[tid - o] : 0;
    int b2 = (tid >= o) ? seq[tid - o] : 0;
    __syncthreads();
    sgt[tid] += a;
    seq[tid] += b2;
    __syncthreads();
  }
  int gt_total = sgt[1023];
  int pg = sgt[tid] - cgt, pe = seq[tid] - ceq;
#pragma unroll
  for (int q = 0; q < TK_CH; q++) {
    if (q < cnt) {
      unsigned long long u = kv[q];
      if (u > T) {
        s_sel[pg++] = i0 + q;
      } else if (u == T) {
        if (pe < need) s_sel[gt_total + pe] = i0 + q;
        pe++;
      }
    }
  }
  __syncthreads();

  // inline decode of the k selected anchors
  const float* pp;
  switch (l) {
    case 0: pp = p0; break;
    case 1: pp = p1; break;
    case 2: pp = p2; break;
    case 3: pp = p3; break;
    default: pp = p4; break;
  }
  const double* regs_l = regs + c_regoff[l];
  double imh = (double)imsizes[n * 2 + 0], imw = (double)imsizes[n * 2 + 1];
  const double BCLIP = 4.1351665567423560; // log(1000/16)
  for (int i = tid; i < k; i += 1024) {
    int aidx = s_sel[i];
    int slot = n * D_PER + c_lvoff[l] + i;
    double lv = lg[aidx];
    double obj = 1.0 / (1.0 + exp(-lv));
    const double* rp = regs_l + ((size_t)n * M + aidx) * 4;
    const float* pr = pp + (size_t)aidx * 4;
    double px1 = pr[0], py1 = pr[1], px2 = pr[2], py2 = pr[3];
    double pw = px2 - px1, ph = py2 - py1;
    double pcx = px1 + 0.5 * pw, pcy = py1 + 0.5 * ph;
    double dx = rp[0], dy = rp[1];
    double dw = fmin(rp[2], BCLIP), dh = fmin(rp[3], BCLIP);
    double cx = dx * pw + pcx, cy = dy * ph + pcy;
    double w = exp(dw) * pw, hh = exp(dh) * ph;
    double x1 = cx - 0.5 * w, y1 = cy - 0.5 * hh;
    double x2 = cx + 0.5 * w, y2 = cy + 0.5 * hh;
    x1 = fmin(fmax(x1, 0.0), imw);
    x2 = fmin(fmax(x2, 0.0), imw);
    y1 = fmin(fmax(y1, 0.0), imh);
    y2 = fmin(fmax(y2, 0.0), imh);
    bool valid = (obj >= 0.5) && ((x2 - x1) >= 1.0) && ((y2 - y1) >= 1.0);
    cand_box[(size_t)slot * 4 + 0] = x1;
    cand_box[(size_t)slot * 4 + 1] = y1;
    cand_box[(size_t)slot * 4 + 2] = x2;
    cand_box[(size_t)slot * 4 + 3] = y2;
    cand_score[slot] = valid ? obj : -(double)INFINITY;
    cand_group[slot] = n * 5 + l;
    cand_valid[slot] = valid ? 1 : 0;
  }
}

// ------- global descending sort (bitonic) + gather (fused) --------------
__global__ __launch_bounds__(1024) void sort_gather_kernel(
    const double* __restrict__ cand_score, const double* __restrict__ cand_box,
    const int* __restrict__ cand_group, const int* __restrict__ cand_valid,
    double* __restrict__ box_s, int* __restrict__ grp_s,
    int* __restrict__ img_s, int* __restrict__ valid_s,
    int* __restrict__ keep_s) {
  __shared__ unsigned long long key[K_PAD]; // 64 KiB
  int tid = threadIdx.x;
  for (int i = tid; i < K_PAD; i += 1024) {
    unsigned long long kk = 0ull;
    if (i < K_TOT) {
      unsigned long long u = d2key(cand_score[i]);
      kk = (u & ~0x1FFFull) | (unsigned long long)i; // slot in low 13 bits
    }
    key[i] = kk;
  }
  __syncthreads();
  for (int k = 2; k <= K_PAD; k <<= 1) {
    for (int j = k >> 1; j > 0; j >>= 1) {
      for (int i = tid; i < K_PAD; i += 1024) {
        int ixj = i ^ j;
        if (ixj > i) {
          unsigned long long a = key[i], b = key[ixj];
          bool sw = ((i & k) == 0) ? (a < b) : (a > b); // descending
          if (sw) { key[i] = b; key[ixj] = a; }
        }
      }
      __syncthreads();
    }
  }
  for (int i = tid; i < K_TOT; i += 1024) {
    int s = (int)(key[i] & 0x1FFFull);
#pragma unroll
    for (int q = 0; q < 4; q++)
      box_s[(size_t)i * 4 + q] = cand_box[(size_t)s * 4 + q];
    int g = cand_group[s];
    grp_s[i] = g;
    img_s[i] = g / 5;
    valid_s[i] = cand_valid[s];
    keep_s[i] = 0;
  }
}

// ---------------- per-group greedy NMS (bitmask) ------------------------
#define MAXM 512
__global__ __launch_bounds__(256) void nms_kernel(
    const double* __restrict__ box_s, const int* __restrict__ grp_s,
    const int* __restrict__ valid_s, int* __restrict__ keep_s) {
  int g = blockIdx.x;
  int tid = threadIdx.x;
  __shared__ int cnt[256];
  __shared__ int mem[MAXM];
  __shared__ double bx[MAXM][4];
  __shared__ unsigned long long mask[MAXM][8];
  const int chunk = (K_TOT + 255) / 256;
  int i0 = tid * chunk, i1 = min(K_TOT, i0 + chunk);
  int c = 0;
  for (int i = i0; i < i1; ++i) c += (grp_s[i] == g && valid_s[i]);
  cnt[tid] = c;
  __syncthreads();
  for (int o = 1; o < 256; o <<= 1) {
    int v = (tid >= o) ? cnt[tid - o] : 0;
    __syncthreads();
    cnt[tid] += v;
    __syncthreads();
  }
  int off = cnt[tid] - c;
  int m = cnt[255];
  for (int i = i0; i < i1; ++i)
    if (grp_s[i] == g && valid_s[i]) mem[off++] = i;
  __syncthreads();
  for (int t = tid; t < m; t += 256) {
    int i = mem[t];
#pragma unroll
    for (int q = 0; q < 4; q++) bx[t][q] = box_s[(size_t)i * 4 + q];
  }
  __syncthreads();
  for (int i = tid; i < m; i += 256) {
    unsigned long long row[8] = {0, 0, 0, 0, 0, 0, 0, 0};
    double ax1 = bx[i][0], ay1 = bx[i][1], ax2 = bx[i][2], ay2 = bx[i][3];
    double areaA = (ax2 - ax1) * (ay2 - ay1);
    for (int j = i + 1; j < m; ++j) {
      double bx1 = bx[j][0], by1 = bx[j][1], bx2 = bx[j][2], by2 = bx[j][3];
      double areaB = (bx2 - bx1) * (by2 - by1);
      double lx = fmax(ax1, bx1), ly = fmax(ay1, by1);
      double rx = fmin(ax2, bx2), ry = fmin(ay2, by2);
      double iw = fmax(rx - lx, 0.0), ih = fmax(ry - ly, 0.0);
      double inter = iw * ih;
      double iou = inter / (areaA + areaB - inter + 1e-9);
      if (iou > 0.7) row[j >> 6] |= (1ull << (j & 63));
    }
#pragma unroll
    for (int w2 = 0; w2 < 8; ++w2) mask[i][w2] = row[w2];
  }
  __syncthreads();
  if (tid == 0) {
    unsigned long long remv[8] = {0, 0, 0, 0, 0, 0, 0, 0};
    for (int i = 0; i < m; ++i) {
      if (!((remv[i >> 6] >> (i & 63)) & 1ull)) {
        keep_s[mem[i]] = 1;
#pragma unroll
        for (int w2 = 0; w2 < 8; ++w2) remv[w2] |= mask[i][w2];
      }
    }
  }
}

// ---------------- per-image top-100 selection + padding ----------------
__global__ __launch_bounds__(256) void select_kernel(
    const double* __restrict__ box_s, const int* __restrict__ img_s,
    const int* __restrict__ keep_s, float* __restrict__ out) {
  int n = blockIdx.x;
  int tid = threadIdx.x;
  __shared__ int cnt[256];
  const int chunk = (K_TOT + 255) / 256;
  int i0 = tid * chunk, i1 = min(K_TOT, i0 + chunk);
  int c = 0;
  for (int i = i0; i < i1; ++i) c += (keep_s[i] && img_s[i] == n);
  cnt[tid] = c;
  __syncthreads();
  for (int o = 1; o < 256; o <<= 1) {
    int v = (tid >= o) ? cnt[tid - o] : 0;
    __syncthreads();
    cnt[tid] += v;
    __syncthreads();
  }
  int pos = cnt[tid] - c;
  int total = cnt[255];
  for (int i = i0; i < i1; ++i) {
    if (keep_s[i] && img_s[i] == n) {
      if (pos < 100) {
#pragma unroll
        for (int q = 0; q < 4; q++)
          out[(n * 100 + pos) * 4 + q] = (float)box_s[(size_t)i * 4 + q];
        out[800 + n * 100 + pos] = (float)n;
      }
      pos++;
    }
  }
  for (int p = total + tid; p < 100; p += 256) {
#pragma unroll
    for (int q = 0; q < 4; q++) out[(n * 100 + p) * 4 + q] = 0.0f;
    out[800 + n * 100 + p] = -1.0f;
  }
}

extern "C" void kernel_launch(void* const* d_in, const int* in_sizes, int n_in,
                              void* d_out, int out_size, void* d_ws,
                              size_t ws_size, hipStream_t stream) {
  (void)in_sizes; (void)n_in; (void)out_size;
  const float* fmap[5];
  const float* priors[5];
  for (int l = 0; l < 5; l++) {
    fmap[l] = (const float*)d_in[2 * l];        // interleaved input order!
    priors[l] = (const float*)d_in[2 * l + 1];
  }
  const float* conv_w = (const float*)d_in[10];
  const float* conv_b = (const float*)d_in[11];
  const float* log_w = (const float*)d_in[12];
  const float* log_b = (const float*)d_in[13];
  const float* reg_w = (const float*)d_in[14];
  const float* reg_b = (const float*)d_in[15];
  const int* imsizes = (const int*)d_in[16];
  float* out = (float*)d_out;

  // h in f64 needs ~66 MB total ws; fall back to f32 h if ws is small.
  bool f64h = ws_size >= (size_t)66000000;

  char* base = (char*)d_ws;
  size_t off = 0;
  auto alloc = [&](size_t bytes) -> void* {
    off = (off + 255) & ~(size_t)255;
    void* p = base + off;
    off += bytes;
    return p;
  };
  double* wT2 = (double*)alloc(589824ull * 8);
  void* hraw = alloc(6831616ull * (f64h ? 8 : 4));
  double* logits = (double*)alloc(80058ull * 8);
  double* regs = (double*)alloc(320232ull * 8);
  double* cand_score = (double*)alloc(K_TOT * 8);
  double* cand_box = (double*)alloc((size_t)K_TOT * 4 * 8);
  int* cand_group = (int*)alloc(K_TOT * 4);
  int* cand_valid = (int*)alloc(K_TOT * 4);
  double* box_s = (double*)alloc((size_t)K_TOT * 4 * 8);
  int* grp_s = (int*)alloc(K_TOT * 4);
  int* img_s = (int*)alloc(K_TOT * 4);
  int* valid_s = (int*)alloc(K_TOT * 4);
  int* keep_s = (int*)alloc(K_TOT * 4);

  transpose_w_kernel<<<2304, 256, 0, stream>>>(conv_w, wT2);

  if (f64h) {
    conv_fused_kernel<double><<<CONV_BLOCKS, 256, 0, stream>>>(
        fmap[0], fmap[1], fmap[2], fmap[3], fmap[4], wT2, conv_b,
        (double*)hraw);
    heads_fused_kernel<double><<<dim3(211, 2), 256, 0, stream>>>(
        (double*)hraw, log_w, log_b, reg_w, reg_b, logits, regs);
  } else {
    conv_fused_kernel<float><<<CONV_BLOCKS, 256, 0, stream>>>(
        fmap[0], fmap[1], fmap[2], fmap[3], fmap[4], wT2, conv_b,
        (float*)hraw);
    heads_fused_kernel<float><<<dim3(211, 2), 256, 0, stream>>>(
        (float*)hraw, log_w, log_b, reg_w, reg_b, logits, regs);
  }
  topk_decode_kernel<<<10, 1024, 0, stream>>>(
      logits, regs, priors[0], priors[1], priors[2], priors[3], priors[4],
      imsizes, cand_score, cand_box, cand_group, cand_valid);
  sort_gather_kernel<<<1, 1024, 0, stream>>>(
      cand_score, cand_box, cand_group, cand_valid, box_s, grp_s, img_s,
      valid_s, keep_s);
  nms_kernel<<<10, 256, 0, stream>>>(box_s, grp_s, valid_s, keep_s);
  select_kernel<<<2, 256, 0, stream>>>(box_s, img_s, keep_s, out);
}

// Round 8
// 1261.933 us; speedup vs baseline: 1.3156x; 1.3156x over previous
//
#include <hip/hip_runtime.h>
#include <math.h>

// RPN forward: fused conv3x3+relu -> fused 1x1 heads ->
// [topk + decode + per-group sort + NMS + compact] (one 10-block kernel) ->
// per-image 5-way merge select. 5 dispatches total.
// Precision: f64 accumulation + f64 logits/regs/h -> all selection decisions
// match the float64 numpy reference exactly (absmax 0 through R2-R7).
// Ladder: R3 reg-dbuf (VGPR 252, occ 11%) FAIL; R4 f32-LDS cvt tax; R5 f64
// LDS occ 29% + L2 blowout; R6 CI4+XCD swizzle 851us (VALU 66%, 73.5M LDS
// conflicts); R7 scalar-weight loads stall (VALU 39%) FAIL -> revert to R6.
// R8: input rows padded 12->13 doubles (bank stride 26, 2-way max = free)
// kills the 4-way input-read conflict (the whole 73.5M); tail fused.

#define N_IMG 2
#define C_CH  256
#define D_PER 2147
#define K_TOT 4294
#define CONV_BLOCKS 1912
#define CPX 239              // CONV_BLOCKS / 8 XCDs (exact)

__constant__ int c_Ml[5]     = {30000, 7500, 1875, 507, 147};
__constant__ int c_kl[5]     = {500, 500, 500, 500, 147};
__constant__ int c_logoff[5] = {0, 60000, 75000, 78750, 79764};   // 6*cumE
__constant__ int c_regoff[5] = {0, 240000, 300000, 315000, 319056}; // 24*cumE
__constant__ int c_fs[5]     = {100, 50, 25, 13, 7};
__constant__ int c_npt[5]    = {13, 7, 4, 2, 1};
__constant__ int c_E[5]      = {10000, 2500, 625, 169, 49};
__constant__ int c_cumbl[6]  = {0, 1352, 1744, 1872, 1904, 1912};
__constant__ int c_hcum[6]   = {0, 157, 197, 207, 210, 211};
__constant__ size_t c_hoff[5] = {0, 5120000, 6400000, 6720000, 6806528};

// ------- weight repack+convert: slabs of 2304 f64 = [ci4][tap9][co64] ----
__global__ void transpose_w_kernel(const float* __restrict__ w,
                                   double* __restrict__ wT2) {
  int i = blockIdx.x * 256 + threadIdx.x;
  if (i >= 589824) return;
  int q = i % 2304;
  int slab = i / 2304;
  int cobi = slab >> 6, ch = slab & 63;
  int ci = q / 576;
  int rem = q % 576;
  int tap = rem / 64, co = rem & 63;
  wT2[i] =
      (double)w[(size_t)(cobi * 64 + co) * 2304 + (ch * 4 + ci) * 9 + tap];
}

// ------- fused conv3x3 (SAME) + bias + relu, all 5 levels, f64 acc -------
// block: 256 thr = 16 px-slots x 16 co-slots; tile 64co x 8x8 px;
// thread: 4co x 4px. CI_CHUNK=4. Input rows padded to 13 doubles
// (bank stride 26 -> max 2-way alias = free; 12 gave 4-way on every read).
template <typename T>
__global__ __launch_bounds__(256) void conv_fused_kernel(
    const float* __restrict__ x0, const float* __restrict__ x1,
    const float* __restrict__ x2, const float* __restrict__ x3,
    const float* __restrict__ x4, const double* __restrict__ wT2,
    const float* __restrict__ bias, T* __restrict__ h) {
  __shared__ double s_in[4 * 130];   // [ci][10 rows x 13 (pad)]
  __shared__ double s_w[2304];       // [ci4][tap][co64]
  int tid = threadIdx.x;
  int bid = (blockIdx.x & 7) * CPX + (blockIdx.x >> 3);  // XCD swizzle
  int l = 0;
  while (bid >= c_cumbl[l + 1]) ++l;
  int r = bid - c_cumbl[l];
  int fs = c_fs[l], npt = c_npt[l];
  int tiles = npt * npt;
  int tile = r % tiles;
  int cn = r / tiles;
  int cobi = cn & 3, n = cn >> 2;
  int ptx = tile % npt, pty = tile / npt;
  int px0 = ptx * 8, py0 = pty * 8;
  int E = fs * fs;
  const float* xl;
  switch (l) {
    case 0: xl = x0; break;
    case 1: xl = x1; break;
    case 2: xl = x2; break;
    case 3: xl = x3; break;
    default: xl = x4; break;
  }
  const float* xn = xl + (size_t)n * C_CH * E;
  T* hl = h + c_hoff[l];

  int tpx = tid & 15, tco = tid >> 4;
  int prow = tpx >> 1, pcol0 = (tpx & 1) * 4;

  int in_dst[2], in_src[2];
#pragma unroll
  for (int it = 0; it < 2; ++it) {
    int idx = tid + it * 256;
    in_dst[it] = -1;
    in_src[it] = -1;
    if (idx < 400) {
      int ci = idx / 100, rr2 = idx % 100;
      int hy = rr2 / 10, hx = rr2 % 10;
      int gy = py0 - 1 + hy, gx = px0 - 1 + hx;
      in_dst[it] = ci * 130 + hy * 13 + hx;
      if (gy >= 0 && gy < fs && gx >= 0 && gx < fs)
        in_src[it] = ci * E + gy * fs + gx;
    }
  }

  double acc[4][4];
#pragma unroll
  for (int i = 0; i < 4; i++)
#pragma unroll
    for (int j = 0; j < 4; j++) acc[i][j] = 0.0;

  const double2* wsrc0 = (const double2*)(wT2 + (size_t)cobi * 64 * 2304);

  for (int ch = 0; ch < 64; ++ch) {
    const float* xc = xn + (size_t)ch * 4 * E;
#pragma unroll
    for (int it = 0; it < 2; ++it) {
      if (in_dst[it] >= 0)
        s_in[in_dst[it]] = (in_src[it] >= 0) ? (double)xc[in_src[it]] : 0.0;
    }
    {
      const double2* src = wsrc0 + (size_t)ch * 1152;
      double2* dst = (double2*)s_w;
#pragma unroll
      for (int k = 0; k < 5; k++) {
        int idx = tid + k * 256;
        if (idx < 1152) dst[idx] = src[idx];
      }
    }
    __syncthreads();
#pragma unroll
    for (int ci = 0; ci < 4; ++ci) {
      const double* inp = &s_in[ci * 130];
      const double* wpb = &s_w[ci * 576];
#pragma unroll
      for (int ky = 0; ky < 3; ++ky) {
        const double* ip = inp + (prow + ky) * 13 + pcol0;
        double d6[6];
#pragma unroll
        for (int j = 0; j < 6; j++) d6[j] = ip[j];
#pragma unroll
        for (int kx = 0; kx < 3; ++kx) {
          const double* wp = wpb + (ky * 3 + kx) * 64 + tco * 4;
          double2 wA = *(const double2*)wp;
          double2 wB = *(const double2*)(wp + 2);
          double w0 = wA.x, w1 = wA.y, w2 = wB.x, w3 = wB.y;
#pragma unroll
          for (int pj = 0; pj < 4; pj++) {
            double iv = d6[pj + kx];
            acc[0][pj] = fma(w0, iv, acc[0][pj]);
            acc[1][pj] = fma(w1, iv, acc[1][pj]);
            acc[2][pj] = fma(w2, iv, acc[2][pj]);
            acc[3][pj] = fma(w3, iv, acc[3][pj]);
          }
        }
      }
    }
    __syncthreads();
  }

  int gy = py0 + prow;
  if (gy < fs) {
#pragma unroll
    for (int coi = 0; coi < 4; ++coi) {
      int co = cobi * 64 + tco * 4 + coi;
      double bb = (double)bias[co];
#pragma unroll
      for (int pj = 0; pj < 4; pj++) {
        int gx = px0 + pcol0 + pj;
        if (gx < fs) {
          double v = acc[coi][pj] + bb;
          hl[((size_t)n * C_CH + co) * E + gy * fs + gx] = (T)fmax(v, 0.0);
        }
      }
    }
  }
}

// ------- fused 1x1 heads: 64 px x 4 c-groups per block, LDS reduce -------
template <typename T>
__global__ __launch_bounds__(256) void heads_fused_kernel(
    const T* __restrict__ h, const float* __restrict__ logw,
    const float* __restrict__ logb, const float* __restrict__ regw,
    const float* __restrict__ regb, double* __restrict__ logits,
    double* __restrict__ regs) {
  __shared__ float s_wh[256][16];
  __shared__ double s_red[4][15][64];
  int tid = threadIdx.x;
  int n = blockIdx.y;
  int cidx = blockIdx.x;
  int l = 0;
  while (cidx >= c_hcum[l + 1]) ++l;
  int chunk = cidx - c_hcum[l];
  int E = c_E[l];
  int px0 = chunk * 64;
  const T* hl = h + c_hoff[l];
  double* logits_l = logits + c_logoff[l];
  double* regs_l = regs + c_regoff[l];

  for (int idx = tid; idx < 4096; idx += 256) {
    int c = idx >> 4, j = idx & 15;
    float v = 0.f;
    if (j < 3) v = logw[j * 256 + c];
    else if (j < 15) v = regw[(j - 3) * 256 + c];
    s_wh[c][j] = v;
  }
  __syncthreads();

  int p = tid & 63, c4 = tid >> 6;
  int pix = px0 + p;
  bool act = pix < E;
  double acc[15];
#pragma unroll
  for (int j = 0; j < 15; j++) acc[j] = 0.0;
  if (act) {
    const T* hp = hl + ((size_t)n * C_CH + c4 * 64) * E + pix;
    for (int cc = 0; cc < 64; ++cc) {
      double hv = (double)hp[(size_t)cc * E];
      const float* wr = &s_wh[c4 * 64 + cc][0];
#pragma unroll
      for (int j = 0; j < 15; j++)
        acc[j] = fma((double)wr[j], hv, acc[j]);
    }
  }
#pragma unroll
  for (int j = 0; j < 15; j++) s_red[c4][j][p] = acc[j];
  __syncthreads();
  if (act) {
    int M = E * 3;
    for (int j = c4; j < 15; j += 4) {
      double v = s_red[0][j][p] + s_red[1][j][p] + s_red[2][j][p] +
                 s_red[3][j][p];
      if (j < 3) {
        logits_l[(size_t)n * M + pix * 3 + j] = v + (double)logb[j];
      } else {
        int rj = j - 3, a = rj >> 2, coord = rj & 3;
        regs_l[((size_t)n * M + pix * 3 + a) * 4 + coord] =
            v + (double)regb[rj];
      }
    }
  }
}

// ------- topk + decode + per-group sort + NMS + compact (10 blocks) ------
__device__ __forceinline__ unsigned long long d2key(double v) {
  unsigned long long ub = (unsigned long long)__double_as_longlong(v);
  return (ub >> 63) ? ~ub : (ub | 0x8000000000000000ull);
}

#define TK_CH 30
union TkShared {
  struct {
    int histw[16][256];
    int hist[256];
    int sgt[1024];
    int seq[1024];
  } a;
  struct {
    unsigned long long u[512];     // sort keys (sorted order)
    int idx[512];                  // sorted -> original topk rank
    int keep[512];
    int ps[512];
    int m;
    double bx[512][4];             // boxes by original topk rank
    unsigned long long mask[512][8];
  } b;
};

__global__ __launch_bounds__(1024) void topk_nms_kernel(
    const double* __restrict__ logits, const double* __restrict__ regs,
    const float* __restrict__ p0, const float* __restrict__ p1,
    const float* __restrict__ p2, const float* __restrict__ p3,
    const float* __restrict__ p4, const int* __restrict__ imsizes,
    double* __restrict__ g_box, unsigned long long* __restrict__ g_u,
    int* __restrict__ g_cnt) {
  __shared__ TkShared sh;
  __shared__ int s_sel[512];
  __shared__ unsigned long long s_prefix;
  __shared__ int s_r;
  int bid = blockIdx.x;
  int n = bid / 5, l = bid % 5;
  int M = c_Ml[l], k = c_kl[l];
  const double* lg = logits + c_logoff[l] + (size_t)n * M;
  int tid = threadIdx.x;
  if (tid == 0) { s_prefix = 0ull; s_r = k; }

  int chunk = (M + 1023) >> 10;
  int i0 = tid * chunk, i1 = min(M, i0 + chunk);
  int cnt = i1 - i0;
  if (cnt < 0) cnt = 0;
  unsigned long long kv[TK_CH];
#pragma unroll
  for (int q = 0; q < TK_CH; q++)
    if (q < cnt) kv[q] = d2key(lg[i0 + q]);
  int wid = tid >> 6;
  __syncthreads();

  for (int pass = 0; pass < 8; ++pass) {
    int shift = 56 - pass * 8;
    for (int i = tid; i < 4096; i += 1024) ((int*)sh.a.histw)[i] = 0;
    __syncthreads();
    unsigned long long pfx = s_prefix;
    int rr = s_r;
#pragma unroll
    for (int q = 0; q < TK_CH; q++) {
      if (q < cnt) {
        unsigned long long u = kv[q];
        if (pass == 0 || (u >> (shift + 8)) == pfx)
          atomicAdd(&sh.a.histw[wid][(int)((u >> shift) & 255ull)], 1);
      }
    }
    __syncthreads();
    if (tid < 256) {
      int s = 0;
#pragma unroll
      for (int w = 0; w < 16; w++) s += sh.a.histw[w][tid];
      sh.a.hist[tid] = s;
    }
    __syncthreads();
    if (tid == 0) {
      int s = 0, beta = 0;
      for (int b = 255; b >= 0; --b) {
        if (s + sh.a.hist[b] >= rr) { beta = b; break; }
        s += sh.a.hist[b];
      }
      s_prefix = (pfx << 8) | (unsigned long long)beta;
      s_r = rr - s;
    }
    __syncthreads();
  }
  unsigned long long T = s_prefix;
  int need = s_r;
  int cgt = 0, ceq = 0;
#pragma unroll
  for (int q = 0; q < TK_CH; q++) {
    if (q < cnt) {
      cgt += (kv[q] > T);
      ceq += (kv[q] == T);
    }
  }
  sh.a.sgt[tid] = cgt;
  sh.a.seq[tid] = ceq;
  __syncthreads();
  for (int o = 1; o < 1024; o <<= 1) {
    int a = (tid >= o) ? sh.a.sgt[tid - o] : 0;
    int b2 = (tid >= o) ? sh.a.seq[tid - o] : 0;
    __syncthreads();
    sh.a.sgt[tid] += a;
    sh.a.seq[tid] += b2;
    __syncthreads();
  }
  int gt_total = sh.a.sgt[1023];
  int pg = sh.a.sgt[tid] - cgt, pe = sh.a.seq[tid] - ceq;
#pragma unroll
  for (int q = 0; q < TK_CH; q++) {
    if (q < cnt) {
      unsigned long long u = kv[q];
      if (u > T) {
        s_sel[pg++] = i0 + q;
      } else if (u == T) {
        if (pe < need) s_sel[gt_total + pe] = i0 + q;
        pe++;
      }
    }
  }
  __syncthreads();   // ---- end topk; s_sel[0..k-1] holds anchors ----

  // decode (tid<512), fill sort keys / boxes
  const float* pp;
  switch (l) {
    case 0: pp = p0; break;
    case 1: pp = p1; break;
    case 2: pp = p2; break;
    case 3: pp = p3; break;
    default: pp = p4; break;
  }
  const double* regs_l = regs + c_regoff[l];
  double imh = (double)imsizes[n * 2 + 0], imw = (double)imsizes[n * 2 + 1];
  const double BCLIP = 4.1351665567423560; // log(1000/16)
  if (tid < 512) {
    unsigned long long key = 0ull;
    sh.b.idx[tid] = tid;
    sh.b.keep[tid] = 0;
    if (tid < k) {
      int aidx = s_sel[tid];
      double lv = lg[aidx];
      double obj = 1.0 / (1.0 + exp(-lv));
      const double* rp = regs_l + ((size_t)n * M + aidx) * 4;
      const float* pr = pp + (size_t)aidx * 4;
      double px1 = pr[0], py1 = pr[1], px2 = pr[2], py2 = pr[3];
      double pw = px2 - px1, ph = py2 - py1;
      double pcx = px1 + 0.5 * pw, pcy = py1 + 0.5 * ph;
      double dx = rp[0], dy = rp[1];
      double dw = fmin(rp[2], BCLIP), dh = fmin(rp[3], BCLIP);
      double cx = dx * pw + pcx, cy = dy * ph + pcy;
      double w = exp(dw) * pw, hh = exp(dh) * ph;
      double x1 = cx - 0.5 * w, y1 = cy - 0.5 * hh;
      double x2 = cx + 0.5 * w, y2 = cy + 0.5 * hh;
      x1 = fmin(fmax(x1, 0.0), imw);
      x2 = fmin(fmax(x2, 0.0), imw);
      y1 = fmin(fmax(y1, 0.0), imh);
      y2 = fmin(fmax(y2, 0.0), imh);
      bool valid = (obj >= 0.5) && ((x2 - x1) >= 1.0) && ((y2 - y1) >= 1.0);
      sh.b.bx[tid][0] = x1;
      sh.b.bx[tid][1] = y1;
      sh.b.bx[tid][2] = x2;
      sh.b.bx[tid][3] = y2;
      if (valid) key = d2key(obj);
    }
    sh.b.u[tid] = key;
  }
  if (tid == 0) sh.b.m = 0;
  __syncthreads();

  // bitonic sort 512 (u desc, ties idx asc). invalid (key 0) sink to tail.
  for (int kk = 2; kk <= 512; kk <<= 1) {
    for (int j = kk >> 1; j > 0; j >>= 1) {
      if (tid < 512) {
        int i = tid, ixj = i ^ j;
        if (ixj > i) {
          unsigned long long ua = sh.b.u[i], ub = sh.b.u[ixj];
          int ia = sh.b.idx[i], ib = sh.b.idx[ixj];
          bool up = ((i & kk) == 0);   // true: want desc order here
          bool aAfterB = (ua < ub) || (ua == ub && ia > ib);
          bool sw = up ? aAfterB : !aAfterB && (ua != ub || ia != ib);
          if (sw) {
            sh.b.u[i] = ub; sh.b.u[ixj] = ua;
            sh.b.idx[i] = ib; sh.b.idx[ixj] = ia;
          }
        }
      }
      __syncthreads();
    }
  }
  // m = number of valid (nonzero keys), contiguous head after sort
  if (tid < 512) {
    if (sh.b.u[tid] != 0ull && (tid == 511 || sh.b.u[tid + 1] == 0ull))
      sh.b.m = tid + 1;
  }
  __syncthreads();
  int m = sh.b.m;

  // suppression masks: row i over j>i (sorted-rank space)
  if (tid < 512 && tid < m) {
    int i = tid;
    const double* A = sh.b.bx[sh.b.idx[i]];
    double ax1 = A[0], ay1 = A[1], ax2 = A[2], ay2 = A[3];
    double areaA = (ax2 - ax1) * (ay2 - ay1);
    unsigned long long row[8] = {0, 0, 0, 0, 0, 0, 0, 0};
    for (int j = i + 1; j < m; ++j) {
      const double* B = sh.b.bx[sh.b.idx[j]];
      double bx1 = B[0], by1 = B[1], bx2 = B[2], by2 = B[3];
      double areaB = (bx2 - bx1) * (by2 - by1);
      double lx = fmax(ax1, bx1), ly = fmax(ay1, by1);
      double rx = fmin(ax2, bx2), ry = fmin(ay2, by2);
      double iw = fmax(rx - lx, 0.0), ih = fmax(ry - ly, 0.0);
      double inter = iw * ih;
      double iou = inter / (areaA + areaB - inter + 1e-9);
      if (iou > 0.7) row[j >> 6] |= (1ull << (j & 63));
    }
#pragma unroll
    for (int w2 = 0; w2 < 8; ++w2) sh.b.mask[i][w2] = row[w2];
  }
  __syncthreads();

  // greedy scan (sorted order = score desc)
  if (tid == 0) {
    unsigned long long remv[8] = {0, 0, 0, 0, 0, 0, 0, 0};
    for (int i = 0; i < m; ++i) {
      if (!((remv[i >> 6] >> (i & 63)) & 1ull)) {
        sh.b.keep[i] = 1;
#pragma unroll
        for (int w2 = 0; w2 < 8; ++w2) remv[w2] |= sh.b.mask[i][w2];
      }
    }
  }
  __syncthreads();

  // compact kept (in sorted order) to global per-group lists
  if (tid < 512) sh.b.ps[tid] = sh.b.keep[tid];
  __syncthreads();
  for (int o = 1; o < 512; o <<= 1) {
    int v = 0;
    if (tid < 512 && tid >= o) v = sh.b.ps[tid - o];
    __syncthreads();
    if (tid < 512) sh.b.ps[tid] += v;
    __syncthreads();
  }
  if (tid < 512 && sh.b.keep[tid]) {
    int pos = sh.b.ps[tid] - 1;
    const double* B = sh.b.bx[sh.b.idx[tid]];
    size_t gbase = (size_t)bid * 512 + pos;
#pragma unroll
    for (int q = 0; q < 4; q++) g_box[gbase * 4 + q] = B[q];
    g_u[gbase] = sh.b.u[tid];
  }
  if (tid == 0) g_cnt[bid] = (m > 0) ? sh.b.ps[511] : 0;
}

// ------- per-image select: 5-way merge of sorted kept lists, top 100 -----
__global__ __launch_bounds__(256) void select_kernel(
    const double* __restrict__ g_box, const unsigned long long* __restrict__ g_u,
    const int* __restrict__ g_cnt, float* __restrict__ out) {
  __shared__ unsigned long long s_u[5][512];
  __shared__ int s_pick[100];
  __shared__ int s_total;
  int n = blockIdx.x;
  int tid = threadIdx.x;
  int cnts[5];
#pragma unroll
  for (int l = 0; l < 5; l++) cnts[l] = g_cnt[n * 5 + l];
  for (int idx = tid; idx < 5 * 512; idx += 256) {
    int l = idx >> 9, r = idx & 511;
    s_u[l][r] = (r < cnts[l]) ? g_u[(size_t)(n * 5 + l) * 512 + r] : 0ull;
  }
  __syncthreads();
  if (tid == 0) {
    int hd[5] = {0, 0, 0, 0, 0};
    int t = 0;
    while (t < 100) {
      int bl = -1;
      unsigned long long bu = 0ull;
      for (int l = 0; l < 5; l++) {   // ties: lower level = lower global idx
        if (hd[l] < cnts[l] && s_u[l][hd[l]] > bu) {
          bu = s_u[l][hd[l]];
          bl = l;
        }
      }
      if (bl < 0) break;
      s_pick[t++] = bl * 512 + hd[bl];
      hd[bl]++;
    }
    s_total = t;
  }
  __syncthreads();
  int total = s_total;
  for (int t = tid; t < 100; t += 256) {
    if (t < total) {
      int pk = s_pick[t];
      int l = pk >> 9, r = pk & 511;
      size_t gbase = (size_t)(n * 5 + l) * 512 + r;
#pragma unroll
      for (int q = 0; q < 4; q++)
        out[(n * 100 + t) * 4 + q] = (float)g_box[gbase * 4 + q];
      out[800 + n * 100 + t] = (float)n;
    } else {
#pragma unroll
      for (int q = 0; q < 4; q++) out[(n * 100 + t) * 4 + q] = 0.0f;
      out[800 + n * 100 + t] = -1.0f;
    }
  }
}

extern "C" void kernel_launch(void* const* d_in, const int* in_sizes, int n_in,
                              void* d_out, int out_size, void* d_ws,
                              size_t ws_size, hipStream_t stream) {
  (void)in_sizes; (void)n_in; (void)out_size;
  const float* fmap[5];
  const float* priors[5];
  for (int l = 0; l < 5; l++) {
    fmap[l] = (const float*)d_in[2 * l];        // interleaved input order!
    priors[l] = (const float*)d_in[2 * l + 1];
  }
  const float* conv_w = (const float*)d_in[10];
  const float* conv_b = (const float*)d_in[11];
  const float* log_w = (const float*)d_in[12];
  const float* log_b = (const float*)d_in[13];
  const float* reg_w = (const float*)d_in[14];
  const float* reg_b = (const float*)d_in[15];
  const int* imsizes = (const int*)d_in[16];
  float* out = (float*)d_out;

  bool f64h = ws_size >= (size_t)66000000;

  char* base = (char*)d_ws;
  size_t off = 0;
  auto alloc = [&](size_t bytes) -> void* {
    off = (off + 255) & ~(size_t)255;
    void* p = base + off;
    off += bytes;
    return p;
  };
  double* wT2 = (double*)alloc(589824ull * 8);
  void* hraw = alloc(6831616ull * (f64h ? 8 : 4));
  double* logits = (double*)alloc(80058ull * 8);
  double* regs = (double*)alloc(320232ull * 8);
  double* g_box = (double*)alloc(10ull * 512 * 4 * 8);
  unsigned long long* g_u = (unsigned long long*)alloc(10ull * 512 * 8);
  int* g_cnt = (int*)alloc(10 * 4);

  transpose_w_kernel<<<2304, 256, 0, stream>>>(conv_w, wT2);

  if (f64h) {
    conv_fused_kernel<double><<<CONV_BLOCKS, 256, 0, stream>>>(
        fmap[0], fmap[1], fmap[2], fmap[3], fmap[4], wT2, conv_b,
        (double*)hraw);
    heads_fused_kernel<double><<<dim3(211, 2), 256, 0, stream>>>(
        (double*)hraw, log_w, log_b, reg_w, reg_b, logits, regs);
  } else {
    conv_fused_kernel<float><<<CONV_BLOCKS, 256, 0, stream>>>(
        fmap[0], fmap[1], fmap[2], fmap[3], fmap[4], wT2, conv_b,
        (float*)hraw);
    heads_fused_kernel<float><<<dim3(211, 2), 256, 0, stream>>>(
        (float*)hraw, log_w, log_b, reg_w, reg_b, logits, regs);
  }
  topk_nms_kernel<<<10, 1024, 0, stream>>>(
      logits, regs, priors[0], priors[1], priors[2], priors[3], priors[4],
      imsizes, g_box, g_u, g_cnt);
  select_kernel<<<2, 256, 0, stream>>>(g_box, g_u, g_cnt, out);
}

// Round 9
// 1131.187 us; speedup vs baseline: 1.4677x; 1.1156x over previous
//
#include <hip/hip_runtime.h>
#include <math.h>

// RPN forward: fused conv3x3+relu -> fused 1x1 heads ->
// [topk + decode + per-group sort + NMS + compact] (one 10-block kernel) ->
// per-image 5-way merge select. 5 dispatches total.
// Precision: f64 accumulation + f64 logits/regs/h -> all selection decisions
// match the float64 numpy reference exactly (absmax 0 through R2-R8).
// Conv ladder: R3 reg-dbuf FAIL(occ); R4 cvt tax; R5 occ+L2 FAIL; R6 851us
// (LDS-BW-bound: VALU 66% = FMA/LDS cycle ratio; input reads 4-way conflict:
// prow*24 mod 32 hits {0,8,16,24} only); R7 scalar-weight stall FAIL;
// R8 stride-13 broke b128 alignment -> 2x LDS instrs, conflicts 2x FAIL.
// R9: stride 14 doubles -> prow*28 mod 32 = 8 distinct quads, 2-way max
// (free), 16B-aligned so ds_read_b128 is kept. Weight reads: broadcast,
// conflict-free ({0,8,16,24} quads but 16-lane same-address broadcast).

#define N_IMG 2
#define C_CH  256
#define D_PER 2147
#define K_TOT 4294
#define CONV_BLOCKS 1912
#define CPX 239              // CONV_BLOCKS / 8 XCDs (exact)

__constant__ int c_Ml[5]     = {30000, 7500, 1875, 507, 147};
__constant__ int c_kl[5]     = {500, 500, 500, 500, 147};
__constant__ int c_logoff[5] = {0, 60000, 75000, 78750, 79764};   // 6*cumE
__constant__ int c_regoff[5] = {0, 240000, 300000, 315000, 319056}; // 24*cumE
__constant__ int c_fs[5]     = {100, 50, 25, 13, 7};
__constant__ int c_npt[5]    = {13, 7, 4, 2, 1};
__constant__ int c_E[5]      = {10000, 2500, 625, 169, 49};
__constant__ int c_cumbl[6]  = {0, 1352, 1744, 1872, 1904, 1912};
__constant__ int c_hcum[6]   = {0, 157, 197, 207, 210, 211};
__constant__ size_t c_hoff[5] = {0, 5120000, 6400000, 6720000, 6806528};

// ------- weight repack+convert: slabs of 2304 f64 = [ci4][tap9][co64] ----
__global__ void transpose_w_kernel(const float* __restrict__ w,
                                   double* __restrict__ wT2) {
  int i = blockIdx.x * 256 + threadIdx.x;
  if (i >= 589824) return;
  int q = i % 2304;
  int slab = i / 2304;
  int cobi = slab >> 6, ch = slab & 63;
  int ci = q / 576;
  int rem = q % 576;
  int tap = rem / 64, co = rem & 63;
  wT2[i] =
      (double)w[(size_t)(cobi * 64 + co) * 2304 + (ch * 4 + ci) * 9 + tap];
}

// ------- fused conv3x3 (SAME) + bias + relu, all 5 levels, f64 acc -------
// block: 256 thr = 16 px-slots x 16 co-slots; tile 64co x 8x8 px;
// thread: 4co x 4px. CI_CHUNK=4. Input rows: 14 doubles (28-dword stride:
// 8 distinct bank-quads, 2-way max, 16B aligned -> b128 kept).
template <typename T>
__global__ __launch_bounds__(256) void conv_fused_kernel(
    const float* __restrict__ x0, const float* __restrict__ x1,
    const float* __restrict__ x2, const float* __restrict__ x3,
    const float* __restrict__ x4, const double* __restrict__ wT2,
    const float* __restrict__ bias, T* __restrict__ h) {
  __shared__ double s_in[4 * 140];   // [ci][10 rows x 14 (pad)]
  __shared__ double s_w[2304];       // [ci4][tap][co64]
  int tid = threadIdx.x;
  int bid = (blockIdx.x & 7) * CPX + (blockIdx.x >> 3);  // XCD swizzle
  int l = 0;
  while (bid >= c_cumbl[l + 1]) ++l;
  int r = bid - c_cumbl[l];
  int fs = c_fs[l], npt = c_npt[l];
  int tiles = npt * npt;
  int tile = r % tiles;
  int cn = r / tiles;
  int cobi = cn & 3, n = cn >> 2;
  int ptx = tile % npt, pty = tile / npt;
  int px0 = ptx * 8, py0 = pty * 8;
  int E = fs * fs;
  const float* xl;
  switch (l) {
    case 0: xl = x0; break;
    case 1: xl = x1; break;
    case 2: xl = x2; break;
    case 3: xl = x3; break;
    default: xl = x4; break;
  }
  const float* xn = xl + (size_t)n * C_CH * E;
  T* hl = h + c_hoff[l];

  int tpx = tid & 15, tco = tid >> 4;
  int prow = tpx >> 1, pcol0 = (tpx & 1) * 4;

  int in_dst[2], in_src[2];
#pragma unroll
  for (int it = 0; it < 2; ++it) {
    int idx = tid + it * 256;
    in_dst[it] = -1;
    in_src[it] = -1;
    if (idx < 400) {
      int ci = idx / 100, rr2 = idx % 100;
      int hy = rr2 / 10, hx = rr2 % 10;
      int gy = py0 - 1 + hy, gx = px0 - 1 + hx;
      in_dst[it] = ci * 140 + hy * 14 + hx;
      if (gy >= 0 && gy < fs && gx >= 0 && gx < fs)
        in_src[it] = ci * E + gy * fs + gx;
    }
  }

  double acc[4][4];
#pragma unroll
  for (int i = 0; i < 4; i++)
#pragma unroll
    for (int j = 0; j < 4; j++) acc[i][j] = 0.0;

  const double2* wsrc0 = (const double2*)(wT2 + (size_t)cobi * 64 * 2304);

  for (int ch = 0; ch < 64; ++ch) {
    const float* xc = xn + (size_t)ch * 4 * E;
#pragma unroll
    for (int it = 0; it < 2; ++it) {
      if (in_dst[it] >= 0)
        s_in[in_dst[it]] = (in_src[it] >= 0) ? (double)xc[in_src[it]] : 0.0;
    }
    {
      const double2* src = wsrc0 + (size_t)ch * 1152;
      double2* dst = (double2*)s_w;
#pragma unroll
      for (int k = 0; k < 5; k++) {
        int idx = tid + k * 256;
        if (idx < 1152) dst[idx] = src[idx];
      }
    }
    __syncthreads();
#pragma unroll
    for (int ci = 0; ci < 4; ++ci) {
      const double* inp = &s_in[ci * 140];
      const double* wpb = &s_w[ci * 576];
#pragma unroll
      for (int ky = 0; ky < 3; ++ky) {
        const double* ip = inp + (prow + ky) * 14 + pcol0;
        double2 a0 = *(const double2*)ip;
        double2 a1 = *(const double2*)(ip + 2);
        double2 a2 = *(const double2*)(ip + 4);
        double d6[6];
        d6[0] = a0.x; d6[1] = a0.y; d6[2] = a1.x;
        d6[3] = a1.y; d6[4] = a2.x; d6[5] = a2.y;
#pragma unroll
        for (int kx = 0; kx < 3; ++kx) {
          const double* wp = wpb + (ky * 3 + kx) * 64 + tco * 4;
          double2 wA = *(const double2*)wp;
          double2 wB = *(const double2*)(wp + 2);
          double w0 = wA.x, w1 = wA.y, w2 = wB.x, w3 = wB.y;
#pragma unroll
          for (int pj = 0; pj < 4; pj++) {
            double iv = d6[pj + kx];
            acc[0][pj] = fma(w0, iv, acc[0][pj]);
            acc[1][pj] = fma(w1, iv, acc[1][pj]);
            acc[2][pj] = fma(w2, iv, acc[2][pj]);
            acc[3][pj] = fma(w3, iv, acc[3][pj]);
          }
        }
      }
    }
    __syncthreads();
  }

  int gy = py0 + prow;
  if (gy < fs) {
#pragma unroll
    for (int coi = 0; coi < 4; ++coi) {
      int co = cobi * 64 + tco * 4 + coi;
      double bb = (double)bias[co];
#pragma unroll
      for (int pj = 0; pj < 4; pj++) {
        int gx = px0 + pcol0 + pj;
        if (gx < fs) {
          double v = acc[coi][pj] + bb;
          hl[((size_t)n * C_CH + co) * E + gy * fs + gx] = (T)fmax(v, 0.0);
        }
      }
    }
  }
}

// ------- fused 1x1 heads: 64 px x 4 c-groups per block, LDS reduce -------
template <typename T>
__global__ __launch_bounds__(256) void heads_fused_kernel(
    const T* __restrict__ h, const float* __restrict__ logw,
    const float* __restrict__ logb, const float* __restrict__ regw,
    const float* __restrict__ regb, double* __restrict__ logits,
    double* __restrict__ regs) {
  __shared__ float s_wh[256][16];
  __shared__ double s_red[4][15][64];
  int tid = threadIdx.x;
  int n = blockIdx.y;
  int cidx = blockIdx.x;
  int l = 0;
  while (cidx >= c_hcum[l + 1]) ++l;
  int chunk = cidx - c_hcum[l];
  int E = c_E[l];
  int px0 = chunk * 64;
  const T* hl = h + c_hoff[l];
  double* logits_l = logits + c_logoff[l];
  double* regs_l = regs + c_regoff[l];

  for (int idx = tid; idx < 4096; idx += 256) {
    int c = idx >> 4, j = idx & 15;
    float v = 0.f;
    if (j < 3) v = logw[j * 256 + c];
    else if (j < 15) v = regw[(j - 3) * 256 + c];
    s_wh[c][j] = v;
  }
  __syncthreads();

  int p = tid & 63, c4 = tid >> 6;
  int pix = px0 + p;
  bool act = pix < E;
  double acc[15];
#pragma unroll
  for (int j = 0; j < 15; j++) acc[j] = 0.0;
  if (act) {
    const T* hp = hl + ((size_t)n * C_CH + c4 * 64) * E + pix;
    for (int cc = 0; cc < 64; ++cc) {
      double hv = (double)hp[(size_t)cc * E];
      const float* wr = &s_wh[c4 * 64 + cc][0];
#pragma unroll
      for (int j = 0; j < 15; j++)
        acc[j] = fma((double)wr[j], hv, acc[j]);
    }
  }
#pragma unroll
  for (int j = 0; j < 15; j++) s_red[c4][j][p] = acc[j];
  __syncthreads();
  if (act) {
    int M = E * 3;
    for (int j = c4; j < 15; j += 4) {
      double v = s_red[0][j][p] + s_red[1][j][p] + s_red[2][j][p] +
                 s_red[3][j][p];
      if (j < 3) {
        logits_l[(size_t)n * M + pix * 3 + j] = v + (double)logb[j];
      } else {
        int rj = j - 3, a = rj >> 2, coord = rj & 3;
        regs_l[((size_t)n * M + pix * 3 + a) * 4 + coord] =
            v + (double)regb[rj];
      }
    }
  }
}

// ------- topk + decode + per-group sort + NMS + compact (10 blocks) ------
__device__ __forceinline__ unsigned long long d2key(double v) {
  unsigned long long ub = (unsigned long long)__double_as_longlong(v);
  return (ub >> 63) ? ~ub : (ub | 0x8000000000000000ull);
}

#define TK_CH 30
union TkShared {
  struct {
    int histw[16][256];
    int hist[256];
    int sgt[1024];
    int seq[1024];
  } a;
  struct {
    unsigned long long u[512];     // sort keys (sorted order)
    int idx[512];                  // sorted -> original topk rank
    int keep[512];
    int ps[512];
    int m;
    double bx[512][4];             // boxes by original topk rank
    unsigned long long mask[512][8];
  } b;
};

__global__ __launch_bounds__(1024) void topk_nms_kernel(
    const double* __restrict__ logits, const double* __restrict__ regs,
    const float* __restrict__ p0, const float* __restrict__ p1,
    const float* __restrict__ p2, const float* __restrict__ p3,
    const float* __restrict__ p4, const int* __restrict__ imsizes,
    double* __restrict__ g_box, unsigned long long* __restrict__ g_u,
    int* __restrict__ g_cnt) {
  __shared__ TkShared sh;
  __shared__ int s_sel[512];
  __shared__ unsigned long long s_prefix;
  __shared__ int s_r;
  int bid = blockIdx.x;
  int n = bid / 5, l = bid % 5;
  int M = c_Ml[l], k = c_kl[l];
  const double* lg = logits + c_logoff[l] + (size_t)n * M;
  int tid = threadIdx.x;
  if (tid == 0) { s_prefix = 0ull; s_r = k; }

  int chunk = (M + 1023) >> 10;
  int i0 = tid * chunk, i1 = min(M, i0 + chunk);
  int cnt = i1 - i0;
  if (cnt < 0) cnt = 0;
  unsigned long long kv[TK_CH];
#pragma unroll
  for (int q = 0; q < TK_CH; q++)
    if (q < cnt) kv[q] = d2key(lg[i0 + q]);
  int wid = tid >> 6;
  __syncthreads();

  for (int pass = 0; pass < 8; ++pass) {
    int shift = 56 - pass * 8;
    for (int i = tid; i < 4096; i += 1024) ((int*)sh.a.histw)[i] = 0;
    __syncthreads();
    unsigned long long pfx = s_prefix;
    int rr = s_r;
#pragma unroll
    for (int q = 0; q < TK_CH; q++) {
      if (q < cnt) {
        unsigned long long u = kv[q];
        if (pass == 0 || (u >> (shift + 8)) == pfx)
          atomicAdd(&sh.a.histw[wid][(int)((u >> shift) & 255ull)], 1);
      }
    }
    __syncthreads();
    if (tid < 256) {
      int s = 0;
#pragma unroll
      for (int w = 0; w < 16; w++) s += sh.a.histw[w][tid];
      sh.a.hist[tid] = s;
    }
    __syncthreads();
    if (tid == 0) {
      int s = 0, beta = 0;
      for (int b = 255; b >= 0; --b) {
        if (s + sh.a.hist[b] >= rr) { beta = b; break; }
        s += sh.a.hist[b];
      }
      s_prefix = (pfx << 8) | (unsigned long long)beta;
      s_r = rr - s;
    }
    __syncthreads();
  }
  unsigned long long T = s_prefix;
  int need = s_r;
  int cgt = 0, ceq = 0;
#pragma unroll
  for (int q = 0; q < TK_CH; q++) {
    if (q < cnt) {
      cgt += (kv[q] > T);
      ceq += (kv[q] == T);
    }
  }
  sh.a.sgt[tid] = cgt;
  sh.a.seq[tid] = ceq;
  __syncthreads();
  for (int o = 1; o < 1024; o <<= 1) {
    int a = (tid >= o) ? sh.a.sgt[tid - o] : 0;
    int b2 = (tid >= o) ? sh.a.seq[tid - o] : 0;
    __syncthreads();
    sh.a.sgt[tid] += a;
    sh.a.seq[tid] += b2;
    __syncthreads();
  }
  int gt_total = sh.a.sgt[1023];
  int pg = sh.a.sgt[tid] - cgt, pe = sh.a.seq[tid] - ceq;
#pragma unroll
  for (int q = 0; q < TK_CH; q++) {
    if (q < cnt) {
      unsigned long long u = kv[q];
      if (u > T) {
        s_sel[pg++] = i0 + q;
      } else if (u == T) {
        if (pe < need) s_sel[gt_total + pe] = i0 + q;
        pe++;
      }
    }
  }
  __syncthreads();   // ---- end topk; s_sel[0..k-1] holds anchors ----

  const float* pp;
  switch (l) {
    case 0: pp = p0; break;
    case 1: pp = p1; break;
    case 2: pp = p2; break;
    case 3: pp = p3; break;
    default: pp = p4; break;
  }
  const double* regs_l = regs + c_regoff[l];
  double imh = (double)imsizes[n * 2 + 0], imw = (double)imsizes[n * 2 + 1];
  const double BCLIP = 4.1351665567423560; // log(1000/16)
  if (tid < 512) {
    unsigned long long key = 0ull;
    sh.b.idx[tid] = tid;
    sh.b.keep[tid] = 0;
    if (tid < k) {
      int aidx = s_sel[tid];
      double lv = lg[aidx];
      double obj = 1.0 / (1.0 + exp(-lv));
      const double* rp = regs_l + ((size_t)n * M + aidx) * 4;
      const float* pr = pp + (size_t)aidx * 4;
      double px1 = pr[0], py1 = pr[1], px2 = pr[2], py2 = pr[3];
      double pw = px2 - px1, ph = py2 - py1;
      double pcx = px1 + 0.5 * pw, pcy = py1 + 0.5 * ph;
      double dx = rp[0], dy = rp[1];
      double dw = fmin(rp[2], BCLIP), dh = fmin(rp[3], BCLIP);
      double cx = dx * pw + pcx, cy = dy * ph + pcy;
      double w = exp(dw) * pw, hh = exp(dh) * ph;
      double x1 = cx - 0.5 * w, y1 = cy - 0.5 * hh;
      double x2 = cx + 0.5 * w, y2 = cy + 0.5 * hh;
      x1 = fmin(fmax(x1, 0.0), imw);
      x2 = fmin(fmax(x2, 0.0), imw);
      y1 = fmin(fmax(y1, 0.0), imh);
      y2 = fmin(fmax(y2, 0.0), imh);
      bool valid = (obj >= 0.5) && ((x2 - x1) >= 1.0) && ((y2 - y1) >= 1.0);
      sh.b.bx[tid][0] = x1;
      sh.b.bx[tid][1] = y1;
      sh.b.bx[tid][2] = x2;
      sh.b.bx[tid][3] = y2;
      if (valid) key = d2key(obj);
    }
    sh.b.u[tid] = key;
  }
  if (tid == 0) sh.b.m = 0;
  __syncthreads();

  // bitonic sort 512 (u desc, ties idx asc). invalid (key 0) sink to tail.
  for (int kk = 2; kk <= 512; kk <<= 1) {
    for (int j = kk >> 1; j > 0; j >>= 1) {
      if (tid < 512) {
        int i = tid, ixj = i ^ j;
        if (ixj > i) {
          unsigned long long ua = sh.b.u[i], ub = sh.b.u[ixj];
          int ia = sh.b.idx[i], ib = sh.b.idx[ixj];
          bool up = ((i & kk) == 0);
          bool aAfterB = (ua < ub) || (ua == ub && ia > ib);
          bool sw = up ? aAfterB : !aAfterB && (ua != ub || ia != ib);
          if (sw) {
            sh.b.u[i] = ub; sh.b.u[ixj] = ua;
            sh.b.idx[i] = ib; sh.b.idx[ixj] = ia;
          }
        }
      }
      __syncthreads();
    }
  }
  if (tid < 512) {
    if (sh.b.u[tid] != 0ull && (tid == 511 || sh.b.u[tid + 1] == 0ull))
      sh.b.m = tid + 1;
  }
  __syncthreads();
  int m = sh.b.m;

  if (tid < 512 && tid < m) {
    int i = tid;
    const double* A = sh.b.bx[sh.b.idx[i]];
    double ax1 = A[0], ay1 = A[1], ax2 = A[2], ay2 = A[3];
    double areaA = (ax2 - ax1) * (ay2 - ay1);
    unsigned long long row[8] = {0, 0, 0, 0, 0, 0, 0, 0};
    for (int j = i + 1; j < m; ++j) {
      const double* B = sh.b.bx[sh.b.idx[j]];
      double bx1 = B[0], by1 = B[1], bx2 = B[2], by2 = B[3];
      double areaB = (bx2 - bx1) * (by2 - by1);
      double lx = fmax(ax1, bx1), ly = fmax(ay1, by1);
      double rx = fmin(ax2, bx2), ry = fmin(ay2, by2);
      double iw = fmax(rx - lx, 0.0), ih = fmax(ry - ly, 0.0);
      double inter = iw * ih;
      double iou = inter / (areaA + areaB - inter + 1e-9);
      if (iou > 0.7) row[j >> 6] |= (1ull << (j & 63));
    }
#pragma unroll
    for (int w2 = 0; w2 < 8; ++w2) sh.b.mask[i][w2] = row[w2];
  }
  __syncthreads();

  if (tid == 0) {
    unsigned long long remv[8] = {0, 0, 0, 0, 0, 0, 0, 0};
    for (int i = 0; i < m; ++i) {
      if (!((remv[i >> 6] >> (i & 63)) & 1ull)) {
        sh.b.keep[i] = 1;
#pragma unroll
        for (int w2 = 0; w2 < 8; ++w2) remv[w2] |= sh.b.mask[i][w2];
      }
    }
  }
  __syncthreads();

  if (tid < 512) sh.b.ps[tid] = sh.b.keep[tid];
  __syncthreads();
  for (int o = 1; o < 512; o <<= 1) {
    int v = 0;
    if (tid < 512 && tid >= o) v = sh.b.ps[tid - o];
    __syncthreads();
    if (tid < 512) sh.b.ps[tid] += v;
    __syncthreads();
  }
  if (tid < 512 && sh.b.keep[tid]) {
    int pos = sh.b.ps[tid] - 1;
    const double* B = sh.b.bx[sh.b.idx[tid]];
    size_t gbase = (size_t)bid * 512 + pos;
#pragma unroll
    for (int q = 0; q < 4; q++) g_box[gbase * 4 + q] = B[q];
    g_u[gbase] = sh.b.u[tid];
  }
  if (tid == 0) g_cnt[bid] = (m > 0) ? sh.b.ps[511] : 0;
}

// ------- per-image select: 5-way merge of sorted kept lists, top 100 -----
__global__ __launch_bounds__(256) void select_kernel(
    const double* __restrict__ g_box, const unsigned long long* __restrict__ g_u,
    const int* __restrict__ g_cnt, float* __restrict__ out) {
  __shared__ unsigned long long s_u[5][512];
  __shared__ int s_pick[100];
  __shared__ int s_total;
  int n = blockIdx.x;
  int tid = threadIdx.x;
  int cnts[5];
#pragma unroll
  for (int l = 0; l < 5; l++) cnts[l] = g_cnt[n * 5 + l];
  for (int idx = tid; idx < 5 * 512; idx += 256) {
    int l = idx >> 9, r = idx & 511;
    s_u[l][r] = (r < cnts[l]) ? g_u[(size_t)(n * 5 + l) * 512 + r] : 0ull;
  }
  __syncthreads();
  if (tid == 0) {
    int hd[5] = {0, 0, 0, 0, 0};
    int t = 0;
    while (t < 100) {
      int bl = -1;
      unsigned long long bu = 0ull;
      for (int l = 0; l < 5; l++) {   // ties: lower level = lower global idx
        if (hd[l] < cnts[l] && s_u[l][hd[l]] > bu) {
          bu = s_u[l][hd[l]];
          bl = l;
        }
      }
      if (bl < 0) break;
      s_pick[t++] = bl * 512 + hd[bl];
      hd[bl]++;
    }
    s_total = t;
  }
  __syncthreads();
  int total = s_total;
  for (int t = tid; t < 100; t += 256) {
    if (t < total) {
      int pk = s_pick[t];
      int l = pk >> 9, r = pk & 511;
      size_t gbase = (size_t)(n * 5 + l) * 512 + r;
#pragma unroll
      for (int q = 0; q < 4; q++)
        out[(n * 100 + t) * 4 + q] = (float)g_box[gbase * 4 + q];
      out[800 + n * 100 + t] = (float)n;
    } else {
#pragma unroll
      for (int q = 0; q < 4; q++) out[(n * 100 + t) * 4 + q] = 0.0f;
      out[800 + n * 100 + t] = -1.0f;
    }
  }
}

extern "C" void kernel_launch(void* const* d_in, const int* in_sizes, int n_in,
                              void* d_out, int out_size, void* d_ws,
                              size_t ws_size, hipStream_t stream) {
  (void)in_sizes; (void)n_in; (void)out_size;
  const float* fmap[5];
  const float* priors[5];
  for (int l = 0; l < 5; l++) {
    fmap[l] = (const float*)d_in[2 * l];        // interleaved input order!
    priors[l] = (const float*)d_in[2 * l + 1];
  }
  const float* conv_w = (const float*)d_in[10];
  const float* conv_b = (const float*)d_in[11];
  const float* log_w = (const float*)d_in[12];
  const float* log_b = (const float*)d_in[13];
  const float* reg_w = (const float*)d_in[14];
  const float* reg_b = (const float*)d_in[15];
  const int* imsizes = (const int*)d_in[16];
  float* out = (float*)d_out;

  bool f64h = ws_size >= (size_t)66000000;

  char* base = (char*)d_ws;
  size_t off = 0;
  auto alloc = [&](size_t bytes) -> void* {
    off = (off + 255) & ~(size_t)255;
    void* p = base + off;
    off += bytes;
    return p;
  };
  double* wT2 = (double*)alloc(589824ull * 8);
  void* hraw = alloc(6831616ull * (f64h ? 8 : 4));
  double* logits = (double*)alloc(80058ull * 8);
  double* regs = (double*)alloc(320232ull * 8);
  double* g_box = (double*)alloc(10ull * 512 * 4 * 8);
  unsigned long long* g_u = (unsigned long long*)alloc(10ull * 512 * 8);
  int* g_cnt = (int*)alloc(10 * 4);

  transpose_w_kernel<<<2304, 256, 0, stream>>>(conv_w, wT2);

  if (f64h) {
    conv_fused_kernel<double><<<CONV_BLOCKS, 256, 0, stream>>>(
        fmap[0], fmap[1], fmap[2], fmap[3], fmap[4], wT2, conv_b,
        (double*)hraw);
    heads_fused_kernel<double><<<dim3(211, 2), 256, 0, stream>>>(
        (double*)hraw, log_w, log_b, reg_w, reg_b, logits, regs);
  } else {
    conv_fused_kernel<float><<<CONV_BLOCKS, 256, 0, stream>>>(
        fmap[0], fmap[1], fmap[2], fmap[3], fmap[4], wT2, conv_b,
        (float*)hraw);
    heads_fused_kernel<float><<<dim3(211, 2), 256, 0, stream>>>(
        (float*)hraw, log_w, log_b, reg_w, reg_b, logits, regs);
  }
  topk_nms_kernel<<<10, 1024, 0, stream>>>(
      logits, regs, priors[0], priors[1], priors[2], priors[3], priors[4],
      imsizes, g_box, g_u, g_cnt);
  select_kernel<<<2, 256, 0, stream>>>(g_box, g_u, g_cnt, out);
}